// Round 16
// baseline (162.028 us; speedup 1.0000x reference)
//
#include <hip/hip_runtime.h>
#include <stdint.h>

typedef unsigned short u16;
typedef __attribute__((ext_vector_type(8))) __bf16 bf16x8;
typedef __attribute__((ext_vector_type(4))) float f32x4;
typedef __attribute__((ext_vector_type(4))) unsigned short u16x4;

__device__ __forceinline__ float bf2f(u16 u){
  unsigned int x = ((unsigned int)u) << 16;
  return __builtin_bit_cast(float, x);
}
__device__ __forceinline__ u16 f2bf(float f){
  unsigned int u = __builtin_bit_cast(unsigned int, f);
  u += 0x7fffu + ((u >> 16) & 1u);   // RNE
  return (u16)(u >> 16);
}
__device__ __forceinline__ float fexp2(float x){ return __builtin_exp2f(x); }
// global -> LDS direct DMA, 16B/lane. LDS dest = wave-uniform base (+lane*16).
__device__ __forceinline__ void lds_load16(const void* g, void* l){
  __builtin_amdgcn_global_load_lds(
      (const __attribute__((address_space(1))) unsigned int*)g,
      (__attribute__((address_space(3))) unsigned int*)l, 16, 0, 0);
}

// ------- transpose+convert: out_bf16[C][R] = in_f32[R][C], 64x64 tiles -------
__global__ __launch_bounds__(256) void transpose64(const float* __restrict__ in,
                                                   u16* __restrict__ out,
                                                   int R, int C){
  __shared__ u16 t[64][65];
  const int c0 = blockIdx.x * 64, r0 = blockIdx.y * 64;
  const int tid = threadIdx.x;
  const int rr = tid >> 3;          // 0..31
  const int cc = (tid & 7) * 8;     // 0..56
#pragma unroll
  for (int i = 0; i < 2; i++){
    int r = i * 32 + rr;
    const float* p = in + (size_t)(r0 + r) * C + c0 + cc;
    f32x4 v0 = *(const f32x4*)p;
    f32x4 v1 = *(const f32x4*)(p + 4);
#pragma unroll
    for (int j = 0; j < 4; j++){ t[r][cc + j] = f2bf(v0[j]); t[r][cc + 4 + j] = f2bf(v1[j]); }
  }
  __syncthreads();
#pragma unroll
  for (int i = 0; i < 2; i++){
    int c = i * 32 + rr;
    u16 tmp[8];
#pragma unroll
    for (int j = 0; j < 8; j++) tmp[j] = t[cc + j][c];
    *(bf16x8*)(out + (size_t)(c0 + c) * R + r0 + cc) = *(const bf16x8*)tmp;
  }
}

// ------- x (f32) -> bf16 flat convert ----------------------------------------
__global__ __launch_bounds__(256) void convert_bf16(const float* __restrict__ in,
                                                    u16* __restrict__ out){
  int t = blockIdx.x * 256 + threadIdx.x;
  const float* p = in + (size_t)t * 8;
  f32x4 v0 = *(const f32x4*)p;
  f32x4 v1 = *(const f32x4*)(p + 4);
  u16 tmp[8];
#pragma unroll
  for (int j = 0; j < 4; j++){ tmp[j] = f2bf(v0[j]); tmp[4 + j] = f2bf(v1[j]); }
  *(bf16x8*)(out + (size_t)t * 8) = *(const bf16x8*)tmp;
}

// ------- vT[bh][d=64][s=2048] = V third of qkv, per-head transposed ----------
__global__ __launch_bounds__(256) void v_transpose(const u16* __restrict__ qkv,
                                                   u16* __restrict__ vT){
  const int S = 2048, LD = 3072;
  __shared__ u16 t[64][65];
  const int bh = blockIdx.y;
  const int b = bh >> 4, h = bh & 15;
  const int s0 = blockIdx.x * 64;
  const u16* src = qkv + (size_t)b * S * LD + 2048 + h * 64;
  const int tid = threadIdx.x;
  const int rr = tid >> 3;
  const int cc = (tid & 7) * 8;
#pragma unroll
  for (int i = 0; i < 2; i++){
    int s = i * 32 + rr;
    bf16x8 v = *(const bf16x8*)(src + (size_t)(s0 + s) * LD + cc);
#pragma unroll
    for (int j = 0; j < 8; j++) t[s][cc + j] = __builtin_bit_cast(u16, (__bf16)v[j]);
  }
  __syncthreads();
  u16* dst = vT + (size_t)bh * 64 * S;
#pragma unroll
  for (int i = 0; i < 2; i++){
    int d = i * 32 + rr;
    u16 tmp[8];
#pragma unroll
    for (int j = 0; j < 8; j++) tmp[j] = t[cc + j][d];
    *(bf16x8*)(dst + (size_t)d * S + s0 + cc) = *(const bf16x8*)tmp;
  }
}

// -------- GEMM (all-bf16, m97 DMA staging + XCD swizzle) ---------------------
// ROPE: fuse RoPE into epilogue for q/k columns (bn<16, wave-uniform).
template<bool OUTF32, bool ROPE>
__global__ __launch_bounds__(256, 2) void gemm_bt(const u16* __restrict__ A,
                                                  const u16* __restrict__ Bt,
                                                  const float* __restrict__ bias,
                                                  void* __restrict__ Cv,
                                                  int M, int N, int K,
                                                  const float* __restrict__ cosb,
                                                  const float* __restrict__ sinb){
  __shared__ u16 As[128 * 32];
  __shared__ u16 Bs[128 * 32];
  // bijective XCD chunking (nwg % 8 == 0 for both call sites)
  const int nx = gridDim.x;
  const int L = blockIdx.x + nx * blockIdx.y;
  const int per = (nx * gridDim.y) >> 3;
  const int wg = (L & 7) * per + (L >> 3);
  const int bn = wg % nx, bm = wg / nx;
  const int tid = threadIdx.x, w = tid >> 6, l = tid & 63;
  const int lo = l & 15, hi = l >> 4;
  const int wr = (w >> 1) * 64, wc = (w & 1) * 64;
  f32x4 acc[4][4] = {};
  const int lrow = l >> 2, lcd = l & 3;   // lane -> row-in-16, chunk

  for (int k0 = 0; k0 < K; k0 += 32){
#pragma unroll
    for (int i = 0; i < 2; i++){
      int row0 = i * 64 + w * 16;
      int row = row0 + lrow;
      int cs = lcd ^ ((row >> 1) & 3);    // pre-swizzled source chunk
      lds_load16(A  + (size_t)(bm * 128 + row) * K + k0 + cs * 8,
                 (char*)As + row0 * 64);
      lds_load16(Bt + (size_t)(bn * 128 + row) * K + k0 + cs * 8,
                 (char*)Bs + row0 * 64);
    }
    __syncthreads();
    bf16x8 a[4], b[4];
#pragma unroll
    for (int mi = 0; mi < 4; mi++){
      int row = wr + mi * 16 + lo;
      unsigned byte = (unsigned)(row * 64 + hi * 16) ^ (((row >> 1) & 3) << 4);
      a[mi] = *(const bf16x8*)((const char*)As + byte);
    }
#pragma unroll
    for (int ni = 0; ni < 4; ni++){
      int row = wc + ni * 16 + lo;
      unsigned byte = (unsigned)(row * 64 + hi * 16) ^ (((row >> 1) & 3) << 4);
      b[ni] = *(const bf16x8*)((const char*)Bs + byte);
    }
    __builtin_amdgcn_s_setprio(1);
#pragma unroll
    for (int mi = 0; mi < 4; mi++)
#pragma unroll
      for (int ni = 0; ni < 4; ni++)
        acc[mi][ni] = __builtin_amdgcn_mfma_f32_16x16x32_bf16(a[mi], b[ni], acc[mi][ni], 0, 0, 0);
    __builtin_amdgcn_s_setprio(0);
    __syncthreads();
  }
  if (ROPE && bn < 16){
    // q/k epilogue: val = acc + bias, then rope pair (even,odd col) via shfl
#pragma unroll
    for (int mi = 0; mi < 4; mi++){
#pragma unroll
      for (int r = 0; r < 4; r++){
        int grow = bm * 128 + wr + mi * 16 + hi * 4 + r;
        int stok = grow & 2047;
#pragma unroll
        for (int ni = 0; ni < 4; ni++){
          int col = bn * 128 + wc + ni * 16 + lo;
          float v = acc[mi][ni][r] + bias[col];
          float partner = __shfl_xor(v, 1, 64);
          int ip = (col & 63) >> 1;
          float c = cosb[stok * 32 + ip], sn = sinb[stok * 32 + ip];
          float res = (lo & 1) ? (partner * sn + v * c) : (v * c - partner * sn);
          ((u16*)Cv)[(size_t)grow * N + col] = f2bf(res);
        }
      }
    }
  } else {
#pragma unroll
    for (int mi = 0; mi < 4; mi++){
#pragma unroll
      for (int r = 0; r < 4; r++){
        int grow = bm * 128 + wr + mi * 16 + hi * 4 + r;
#pragma unroll
        for (int ni = 0; ni < 4; ni++){
          int col = bn * 128 + wc + ni * 16 + lo;
          float v = acc[mi][ni][r] + bias[col];
          if (OUTF32)
            ((float*)Cv)[(size_t)grow * N + col] = v;
          else
            ((u16*)Cv)[(size_t)grow * N + col] = f2bf(v);
        }
      }
    }
  }
}

// ---- flash attention: 1-wave/1-tile blocks, 32-key LDS-DMA K dbuf -----------
// Grid 4096 (= 16 blocks/CU -> 4 waves/SIMD): bh = L & 31 (32%8==0 -> head
// pinned to one XCD, K/V L2-local), T = 127 - (L>>5) (heavy first; per-CU
// T-values strided by 8 -> near-uniform CU work sums).
// LDS 9.7 KB: Ks[2][32x64] DMA dbuf + Ps (72B stride, conflict-free).
// No __syncthreads; compiler vmcnt/lgkmcnt orders DMA->ds_read.
__global__ __launch_bounds__(64, 4) void flash_attn(const u16* __restrict__ qkv,
                                                    const u16* __restrict__ vT,
                                                    u16* __restrict__ Oout){
  const int S = 2048, LD = 3072;
  const int L = blockIdx.x;
  const int bh = L & 31;
  const int T = 127 - (L >> 5);
  const int b = bh >> 4, h = bh & 15;
  const u16* base = qkv + (size_t)b * S * LD;
  const u16* Qp = base + h * 64;
  const u16* Kp = base + 1024 + h * 64;
  const u16* Vb = vT + (size_t)bh * 64 * S;
  const int l = threadIdx.x & 63;
  const int lo = l & 15, hi = l >> 4;
  __shared__ u16 Ks[2][32 * 64];            // 32 keys x 64 d, double-buffered
  __shared__ u16 Ps[16 * 36];               // P roundtrip, 72B row stride

  const float QSC = 0.125f * 1.44269504089f;  // -> log2 domain
  const int srow8 = l >> 3;
  const int scs = (l & 7) ^ srow8;          // DMA source chunk (row&7==l>>3)

  const int q0 = T * 16;
  const int qrow = q0 + lo;
  const int nkt = (T >> 1) + 1;             // 32-key tiles

  bf16x8 qf[2];
#pragma unroll
  for (int c = 0; c < 2; c++){
    bf16x8 qv = *(const bf16x8*)(Qp + (size_t)qrow * LD + c * 32 + hi * 8);
#pragma unroll
    for (int j = 0; j < 8; j++) qf[c][j] = (__bf16)((float)qv[j] * QSC);
  }

  f32x4 o[4] = {};
  float m_r = -1e30f, l_par = 0.f;

  // prologue: stage K tile 0 into buf 0 (4 x 1KB issues)
#pragma unroll
  for (int i = 0; i < 4; i++)
    lds_load16(Kp + (size_t)(i * 8 + srow8) * LD + scs * 8,
               (char*)&Ks[0][0] + i * 1024);

  int cur = 0;
  for (int kt = 0; kt < nkt; kt++){
    // ---- V^T B-frags issued first (fly during lgkm wait on K ds_reads) ----
    bf16x8 vb[4];
#pragma unroll
    for (int fd = 0; fd < 4; fd++)
      vb[fd] = *(const bf16x8*)(Vb + (size_t)(fd * 16 + lo) * S + kt * 32 + hi * 8);
    // ---- K frags from Ks[cur] (vmcnt wait covers only older DMA) ----
    bf16x8 kb[2][2];
#pragma unroll
    for (int c = 0; c < 2; c++)
#pragma unroll
      for (int f = 0; f < 2; f++){
        int srow = f * 16 + lo;
        unsigned byte = ((unsigned)(srow * 128 + c * 64 + hi * 16)) ^ ((lo & 7) << 4);
        kb[c][f] = *(const bf16x8*)((const char*)&Ks[cur][0] + byte);
      }
    // ---- issue next K stage (prefetch, drains next iteration) ----
    if (kt + 1 < nkt){
#pragma unroll
      for (int i = 0; i < 4; i++)
        lds_load16(Kp + (size_t)((kt + 1) * 32 + i * 8 + srow8) * LD + scs * 8,
                   (char*)&Ks[cur ^ 1][0] + i * 1024);
    }
    // ---- S^T = K * Q^T (log2 domain) ----
    f32x4 sa[2] = {};
    __builtin_amdgcn_s_setprio(1);
#pragma unroll
    for (int c = 0; c < 2; c++)
#pragma unroll
      for (int f = 0; f < 2; f++)
        sa[f] = __builtin_amdgcn_mfma_f32_16x16x32_bf16(kb[c][f], qf[c], sa[f], 0, 0, 0);
    __builtin_amdgcn_s_setprio(0);
    // ---- causal mask: only the last K-tile can cross the diagonal ----
    if (kt == nkt - 1){
#pragma unroll
      for (int f = 0; f < 2; f++){
        int key0 = kt * 32 + f * 16 + hi * 4;
#pragma unroll
        for (int r = 0; r < 4; r++)
          if (key0 + r > qrow) sa[f][r] = -1e30f;
      }
    }
    // ---- defer-max online softmax (common path: no cross-lane ops) ----
    float pmax = sa[0][0];
#pragma unroll
    for (int f = 0; f < 2; f++)
#pragma unroll
      for (int r = 0; r < 4; r++) pmax = fmaxf(pmax, sa[f][r]);
    if (!__all(pmax - m_r <= 11.5f)){
      float rowmax = fmaxf(pmax, __shfl_xor(pmax, 16, 64));
      rowmax = fmaxf(rowmax, __shfl_xor(rowmax, 32, 64));
      float mnew = fmaxf(m_r, rowmax);
      float corr = fexp2(m_r - mnew);
      m_r = mnew;
      l_par *= corr;
      float corr_q[4];
#pragma unroll
      for (int r = 0; r < 4; r++) corr_q[r] = __shfl(corr, hi * 4 + r, 64);
#pragma unroll
      for (int fd = 0; fd < 4; fd++)
#pragma unroll
        for (int r = 0; r < 4; r++) o[fd][r] *= corr_q[r];
    }
    float psum = 0.f;
#pragma unroll
    for (int f = 0; f < 2; f++){
      u16x4 pk;
#pragma unroll
      for (int r = 0; r < 4; r++){
        float pv = fexp2(sa[f][r] - m_r);
        psum += pv;
        pk[r] = f2bf(pv);
      }
      *(u16x4*)((char*)Ps + lo * 72 + f * 32 + hi * 8) = pk;
    }
    l_par += psum;
    // ---- P[q=lo][k] read back as A-frag (single bf16x8) ----
    bf16x8 pa = *(const bf16x8*)((const char*)Ps + lo * 72 + hi * 16);
    // ---- O += P V ----
    __builtin_amdgcn_s_setprio(1);
#pragma unroll
    for (int fd = 0; fd < 4; fd++)
      o[fd] = __builtin_amdgcn_mfma_f32_16x16x32_bf16(pa, vb[fd], o[fd], 0, 0, 0);
    __builtin_amdgcn_s_setprio(0);
    cur ^= 1;
  }
  // ---- final l reduce + normalize + store ----
  float lsum = l_par;
  lsum += __shfl_xor(lsum, 16, 64);
  lsum += __shfl_xor(lsum, 32, 64);
  float linv = 1.0f / lsum;
  float inv_q[4];
#pragma unroll
  for (int r = 0; r < 4; r++) inv_q[r] = __shfl(linv, hi * 4 + r, 64);
#pragma unroll
  for (int r = 0; r < 4; r++){
    int srow = q0 + hi * 4 + r;
    u16* orow = Oout + (size_t)(b * S + srow) * 1024 + h * 64;
#pragma unroll
    for (int fd = 0; fd < 4; fd++)
      orow[fd * 16 + lo] = f2bf(o[fd][r] * inv_q[r]);
  }
}

extern "C" void kernel_launch(void* const* d_in, const int* in_sizes, int n_in,
                              void* d_out, int out_size, void* d_ws, size_t ws_size,
                              hipStream_t stream){
  const float* x     = (const float*)d_in[0];
  const float* w_qkv = (const float*)d_in[1];
  const float* b_qkv = (const float*)d_in[2];
  const float* w_out = (const float*)d_in[3];
  const float* b_out = (const float*)d_in[4];
  const float* cosb  = (const float*)d_in[5];
  const float* sinb  = (const float*)d_in[6];
  // d_in[7] = mask: causal, implemented analytically.
  float* out = (float*)d_out;
  char* ws = (char*)d_ws;
  u16* qkv  = (u16*)(ws);               // bf16 [4096][3072]   25.2 MB
  u16* attn = (u16*)(ws + 25165824);    // bf16 [4096][1024]    8.4 MB
  u16* xbf  = attn;                     // x bf16 — dead before flash writes attn
  u16* wT2  = (u16*)(ws + 33554432);    // w_out^T bf16 [1024][1024]  2.1 MB
  u16* wT1  = (u16*)(ws + 35651584);    // w_qkv^T bf16 [3072][1024]  6.3 MB
  u16* vT   = (u16*)(ws + 35651584);    // vT — overlaps wT1 (dead after GEMM1)

  transpose64<<<dim3(48, 16), 256, 0, stream>>>(w_qkv, wT1, 1024, 3072);
  transpose64<<<dim3(16, 16), 256, 0, stream>>>(w_out, wT2, 1024, 1024);
  convert_bf16<<<2048, 256, 0, stream>>>(x, xbf);
  gemm_bt<false, true ><<<dim3(24, 32), 256, 0, stream>>>(xbf, wT1, b_qkv, qkv,
                                                          4096, 3072, 1024, cosb, sinb);
  v_transpose<<<dim3(32, 32), 256, 0, stream>>>(qkv, vT);
  flash_attn<<<4096, 64, 0, stream>>>(qkv, vT, attn);
  gemm_bt<true , false><<<dim3(8, 32), 256, 0, stream>>>(attn, wT2, b_out, out,
                                                         4096, 1024, 1024, cosb, sinb);
}

// Round 17
// 157.030 us; speedup vs baseline: 1.0318x; 1.0318x over previous
//
#include <hip/hip_runtime.h>
#include <stdint.h>

typedef unsigned short u16;
typedef __attribute__((ext_vector_type(8))) __bf16 bf16x8;
typedef __attribute__((ext_vector_type(4))) float f32x4;
typedef __attribute__((ext_vector_type(4))) unsigned short u16x4;

__device__ __forceinline__ float bf2f(u16 u){
  unsigned int x = ((unsigned int)u) << 16;
  return __builtin_bit_cast(float, x);
}
// native f32->bf16 (RNE): compiler emits v_cvt_pk_bf16_f32 for pairs
__device__ __forceinline__ u16 f2bf(float f){
  return __builtin_bit_cast(u16, (__bf16)f);
}
__device__ __forceinline__ float fexp2(float x){ return __builtin_exp2f(x); }
// global -> LDS direct DMA, 16B/lane. LDS dest = wave-uniform base (+lane*16).
__device__ __forceinline__ void lds_load16(const void* g, void* l){
  __builtin_amdgcn_global_load_lds(
      (const __attribute__((address_space(1))) unsigned int*)g,
      (__attribute__((address_space(3))) unsigned int*)l, 16, 0, 0);
}

// ------- transpose+convert: out_bf16[C][R] = in_f32[R][C], 64x64 tiles -------
__global__ __launch_bounds__(256) void transpose64(const float* __restrict__ in,
                                                   u16* __restrict__ out,
                                                   int R, int C){
  __shared__ u16 t[64][65];
  const int c0 = blockIdx.x * 64, r0 = blockIdx.y * 64;
  const int tid = threadIdx.x;
  const int rr = tid >> 3;          // 0..31
  const int cc = (tid & 7) * 8;     // 0..56
#pragma unroll
  for (int i = 0; i < 2; i++){
    int r = i * 32 + rr;
    const float* p = in + (size_t)(r0 + r) * C + c0 + cc;
    f32x4 v0 = *(const f32x4*)p;
    f32x4 v1 = *(const f32x4*)(p + 4);
#pragma unroll
    for (int j = 0; j < 4; j++){ t[r][cc + j] = f2bf(v0[j]); t[r][cc + 4 + j] = f2bf(v1[j]); }
  }
  __syncthreads();
#pragma unroll
  for (int i = 0; i < 2; i++){
    int c = i * 32 + rr;
    u16 tmp[8];
#pragma unroll
    for (int j = 0; j < 8; j++) tmp[j] = t[cc + j][c];
    *(bf16x8*)(out + (size_t)(c0 + c) * R + r0 + cc) = *(const bf16x8*)tmp;
  }
}

// ------- x (f32) -> bf16 flat convert ----------------------------------------
__global__ __launch_bounds__(256) void convert_bf16(const float* __restrict__ in,
                                                    u16* __restrict__ out){
  int t = blockIdx.x * 256 + threadIdx.x;
  const float* p = in + (size_t)t * 8;
  f32x4 v0 = *(const f32x4*)p;
  f32x4 v1 = *(const f32x4*)(p + 4);
  u16 tmp[8];
#pragma unroll
  for (int j = 0; j < 4; j++){ tmp[j] = f2bf(v0[j]); tmp[4 + j] = f2bf(v1[j]); }
  *(bf16x8*)(out + (size_t)t * 8) = *(const bf16x8*)tmp;
}

// ------- vT[bh][d=64][s=2048] = V third of qkv, per-head transposed ----------
__global__ __launch_bounds__(256) void v_transpose(const u16* __restrict__ qkv,
                                                   u16* __restrict__ vT){
  const int S = 2048, LD = 3072;
  __shared__ u16 t[64][65];
  const int bh = blockIdx.y;
  const int b = bh >> 4, h = bh & 15;
  const int s0 = blockIdx.x * 64;
  const u16* src = qkv + (size_t)b * S * LD + 2048 + h * 64;
  const int tid = threadIdx.x;
  const int rr = tid >> 3;
  const int cc = (tid & 7) * 8;
#pragma unroll
  for (int i = 0; i < 2; i++){
    int s = i * 32 + rr;
    bf16x8 v = *(const bf16x8*)(src + (size_t)(s0 + s) * LD + cc);
#pragma unroll
    for (int j = 0; j < 8; j++) t[s][cc + j] = __builtin_bit_cast(u16, (__bf16)v[j]);
  }
  __syncthreads();
  u16* dst = vT + (size_t)bh * 64 * S;
#pragma unroll
  for (int i = 0; i < 2; i++){
    int d = i * 32 + rr;
    u16 tmp[8];
#pragma unroll
    for (int j = 0; j < 8; j++) tmp[j] = t[cc + j][d];
    *(bf16x8*)(dst + (size_t)d * S + s0 + cc) = *(const bf16x8*)tmp;
  }
}

// -------- GEMM (all-bf16, m97 DMA staging + XCD swizzle) ---------------------
// ROPE: fuse RoPE into epilogue for q/k columns (bn<16, wave-uniform).
template<bool OUTF32, bool ROPE>
__global__ __launch_bounds__(256, 2) void gemm_bt(const u16* __restrict__ A,
                                                  const u16* __restrict__ Bt,
                                                  const float* __restrict__ bias,
                                                  void* __restrict__ Cv,
                                                  int M, int N, int K,
                                                  const float* __restrict__ cosb,
                                                  const float* __restrict__ sinb){
  __shared__ u16 As[128 * 32];
  __shared__ u16 Bs[128 * 32];
  // bijective XCD chunking (nwg % 8 == 0 for both call sites)
  const int nx = gridDim.x;
  const int L = blockIdx.x + nx * blockIdx.y;
  const int per = (nx * gridDim.y) >> 3;
  const int wg = (L & 7) * per + (L >> 3);
  const int bn = wg % nx, bm = wg / nx;
  const int tid = threadIdx.x, w = tid >> 6, l = tid & 63;
  const int lo = l & 15, hi = l >> 4;
  const int wr = (w >> 1) * 64, wc = (w & 1) * 64;
  f32x4 acc[4][4] = {};
  const int lrow = l >> 2, lcd = l & 3;   // lane -> row-in-16, chunk

  for (int k0 = 0; k0 < K; k0 += 32){
#pragma unroll
    for (int i = 0; i < 2; i++){
      int row0 = i * 64 + w * 16;
      int row = row0 + lrow;
      int cs = lcd ^ ((row >> 1) & 3);    // pre-swizzled source chunk
      lds_load16(A  + (size_t)(bm * 128 + row) * K + k0 + cs * 8,
                 (char*)As + row0 * 64);
      lds_load16(Bt + (size_t)(bn * 128 + row) * K + k0 + cs * 8,
                 (char*)Bs + row0 * 64);
    }
    __syncthreads();
    bf16x8 a[4], b[4];
#pragma unroll
    for (int mi = 0; mi < 4; mi++){
      int row = wr + mi * 16 + lo;
      unsigned byte = (unsigned)(row * 64 + hi * 16) ^ (((row >> 1) & 3) << 4);
      a[mi] = *(const bf16x8*)((const char*)As + byte);
    }
#pragma unroll
    for (int ni = 0; ni < 4; ni++){
      int row = wc + ni * 16 + lo;
      unsigned byte = (unsigned)(row * 64 + hi * 16) ^ (((row >> 1) & 3) << 4);
      b[ni] = *(const bf16x8*)((const char*)Bs + byte);
    }
    __builtin_amdgcn_s_setprio(1);
#pragma unroll
    for (int mi = 0; mi < 4; mi++)
#pragma unroll
      for (int ni = 0; ni < 4; ni++)
        acc[mi][ni] = __builtin_amdgcn_mfma_f32_16x16x32_bf16(a[mi], b[ni], acc[mi][ni], 0, 0, 0);
    __builtin_amdgcn_s_setprio(0);
    __syncthreads();
  }
  if (ROPE && bn < 16){
    // q/k epilogue: val = acc + bias, then rope pair (even,odd col) via shfl
#pragma unroll
    for (int mi = 0; mi < 4; mi++){
#pragma unroll
      for (int r = 0; r < 4; r++){
        int grow = bm * 128 + wr + mi * 16 + hi * 4 + r;
        int stok = grow & 2047;
#pragma unroll
        for (int ni = 0; ni < 4; ni++){
          int col = bn * 128 + wc + ni * 16 + lo;
          float v = acc[mi][ni][r] + bias[col];
          float partner = __shfl_xor(v, 1, 64);
          int ip = (col & 63) >> 1;
          float c = cosb[stok * 32 + ip], sn = sinb[stok * 32 + ip];
          float res = (lo & 1) ? (partner * sn + v * c) : (v * c - partner * sn);
          ((u16*)Cv)[(size_t)grow * N + col] = f2bf(res);
        }
      }
    }
  } else {
#pragma unroll
    for (int mi = 0; mi < 4; mi++){
#pragma unroll
      for (int r = 0; r < 4; r++){
        int grow = bm * 128 + wr + mi * 16 + hi * 4 + r;
#pragma unroll
        for (int ni = 0; ni < 4; ni++){
          int col = bn * 128 + wc + ni * 16 + lo;
          float v = acc[mi][ni][r] + bias[col];
          if (OUTF32)
            ((float*)Cv)[(size_t)grow * N + col] = v;
          else
            ((u16*)Cv)[(size_t)grow * N + col] = f2bf(v);
        }
      }
    }
  }
}

// ---- flash attention: 1-wave blocks, 32-key LDS-DMA K dbuf, 2-tile balance --
// Grid 2048: bh = L & 31 (head pinned to one XCD, K/V L2-local), bx = L >> 5;
// block handles q-tiles {127-bx, bx} -> exactly 65 32-key iterations (uniform).
// VALU-trimmed softmax: native cvt_pk bf16, max3-tree, pairwise psum,
// P-write issued before sum. No __syncthreads anywhere.
__global__ __launch_bounds__(64, 4) void flash_attn(const u16* __restrict__ qkv,
                                                    const u16* __restrict__ vT,
                                                    u16* __restrict__ Oout){
  const int S = 2048, LD = 3072;
  const int L = blockIdx.x;
  const int bh = L & 31;
  const int bx = L >> 5;
  const int b = bh >> 4, h = bh & 15;
  const u16* base = qkv + (size_t)b * S * LD;
  const u16* Qp = base + h * 64;
  const u16* Kp = base + 1024 + h * 64;
  const u16* Vb = vT + (size_t)bh * 64 * S;
  const int l = threadIdx.x & 63;
  const int lo = l & 15, hi = l >> 4;
  __shared__ u16 Ks[2][32 * 64];            // 32 keys x 64 d, double-buffered
  __shared__ u16 Ps[16 * 36];               // P roundtrip, 72B row stride

  const float QSC = 0.125f * 1.44269504089f;  // -> log2 domain
  const int srow8 = l >> 3;
  const int scs = (l & 7) ^ srow8;          // DMA source chunk (row&7==l>>3)

  const int tiles0 = 127 - bx;              // heavy tile first
  const int tiles1 = bx;

#pragma unroll 1
  for (int tsel = 0; tsel < 2; tsel++){
    const int T = tsel ? tiles1 : tiles0;
    const int q0 = T * 16;
    const int qrow = q0 + lo;
    const int nkt = (T >> 1) + 1;           // 32-key tiles

    bf16x8 qf[2];
#pragma unroll
    for (int c = 0; c < 2; c++){
      bf16x8 qv = *(const bf16x8*)(Qp + (size_t)qrow * LD + c * 32 + hi * 8);
#pragma unroll
      for (int j = 0; j < 8; j++) qf[c][j] = (__bf16)((float)qv[j] * QSC);
    }

    f32x4 o[4] = {};
    float m_r = -1e30f, l_par = 0.f;

    // prologue: stage K tile 0 into buf 0 (4 x 1KB issues)
#pragma unroll
    for (int i = 0; i < 4; i++)
      lds_load16(Kp + (size_t)(i * 8 + srow8) * LD + scs * 8,
                 (char*)&Ks[0][0] + i * 1024);

    int cur = 0;
    for (int kt = 0; kt < nkt; kt++){
      // ---- V^T B-frags issued first (fly during lgkm wait on K ds_reads) ----
      bf16x8 vb[4];
#pragma unroll
      for (int fd = 0; fd < 4; fd++)
        vb[fd] = *(const bf16x8*)(Vb + (size_t)(fd * 16 + lo) * S + kt * 32 + hi * 8);
      // ---- K frags from Ks[cur] (vmcnt wait covers only older DMA) ----
      bf16x8 kb[2][2];
#pragma unroll
      for (int c = 0; c < 2; c++)
#pragma unroll
        for (int f = 0; f < 2; f++){
          int srow = f * 16 + lo;
          unsigned byte = ((unsigned)(srow * 128 + c * 64 + hi * 16)) ^ ((lo & 7) << 4);
          kb[c][f] = *(const bf16x8*)((const char*)&Ks[cur][0] + byte);
        }
      // ---- issue next K stage (prefetch, drains next iteration) ----
      if (kt + 1 < nkt){
#pragma unroll
        for (int i = 0; i < 4; i++)
          lds_load16(Kp + (size_t)((kt + 1) * 32 + i * 8 + srow8) * LD + scs * 8,
                     (char*)&Ks[cur ^ 1][0] + i * 1024);
      }
      // ---- S^T = K * Q^T (log2 domain) ----
      f32x4 sa[2] = {};
      __builtin_amdgcn_s_setprio(1);
#pragma unroll
      for (int c = 0; c < 2; c++)
#pragma unroll
        for (int f = 0; f < 2; f++)
          sa[f] = __builtin_amdgcn_mfma_f32_16x16x32_bf16(kb[c][f], qf[c], sa[f], 0, 0, 0);
      __builtin_amdgcn_s_setprio(0);
      // ---- causal mask: only the last K-tile can cross the diagonal ----
      if (kt == nkt - 1){
#pragma unroll
        for (int f = 0; f < 2; f++){
          int key0 = kt * 32 + f * 16 + hi * 4;
#pragma unroll
          for (int r = 0; r < 4; r++)
            if (key0 + r > qrow) sa[f][r] = -1e30f;
        }
      }
      // ---- defer-max online softmax (max3-tree; no cross-lane common path) --
      float pmax = fmaxf(
          fmaxf(fmaxf(sa[0][0], sa[0][1]), fmaxf(sa[0][2], sa[0][3])),
          fmaxf(fmaxf(sa[1][0], sa[1][1]), fmaxf(sa[1][2], sa[1][3])));
      if (!__all(pmax - m_r <= 11.5f)){
        float rowmax = fmaxf(pmax, __shfl_xor(pmax, 16, 64));
        rowmax = fmaxf(rowmax, __shfl_xor(rowmax, 32, 64));
        float mnew = fmaxf(m_r, rowmax);
        float corr = fexp2(m_r - mnew);
        m_r = mnew;
        l_par *= corr;
        float corr_q[4];
#pragma unroll
        for (int r = 0; r < 4; r++) corr_q[r] = __shfl(corr, hi * 4 + r, 64);
#pragma unroll
        for (int fd = 0; fd < 4; fd++)
#pragma unroll
          for (int r = 0; r < 4; r++) o[fd][r] *= corr_q[r];
      }
      // exp2 -> pack+write P first (LDS latency overlaps the sum), then sum
      float pv[2][4];
#pragma unroll
      for (int f = 0; f < 2; f++)
#pragma unroll
        for (int r = 0; r < 4; r++) pv[f][r] = fexp2(sa[f][r] - m_r);
#pragma unroll
      for (int f = 0; f < 2; f++){
        u16x4 pk;
#pragma unroll
        for (int r = 0; r < 4; r++) pk[r] = f2bf(pv[f][r]);
        *(u16x4*)((char*)Ps + lo * 72 + f * 32 + hi * 8) = pk;
      }
      l_par += ((pv[0][0] + pv[0][1]) + (pv[0][2] + pv[0][3]))
             + ((pv[1][0] + pv[1][1]) + (pv[1][2] + pv[1][3]));
      // ---- P[q=lo][k] read back as A-frag (single bf16x8) ----
      bf16x8 pa = *(const bf16x8*)((const char*)Ps + lo * 72 + hi * 16);
      // ---- O += P V ----
      __builtin_amdgcn_s_setprio(1);
#pragma unroll
      for (int fd = 0; fd < 4; fd++)
        o[fd] = __builtin_amdgcn_mfma_f32_16x16x32_bf16(pa, vb[fd], o[fd], 0, 0, 0);
      __builtin_amdgcn_s_setprio(0);
      cur ^= 1;
    }
    // ---- final l reduce + normalize + store ----
    float lsum = l_par;
    lsum += __shfl_xor(lsum, 16, 64);
    lsum += __shfl_xor(lsum, 32, 64);
    float linv = 1.0f / lsum;
    float inv_q[4];
#pragma unroll
    for (int r = 0; r < 4; r++) inv_q[r] = __shfl(linv, hi * 4 + r, 64);
#pragma unroll
    for (int r = 0; r < 4; r++){
      int srow = q0 + hi * 4 + r;
      u16* orow = Oout + (size_t)(b * S + srow) * 1024 + h * 64;
#pragma unroll
      for (int fd = 0; fd < 4; fd++)
        orow[fd * 16 + lo] = f2bf(o[fd][r] * inv_q[r]);
    }
  }
}

extern "C" void kernel_launch(void* const* d_in, const int* in_sizes, int n_in,
                              void* d_out, int out_size, void* d_ws, size_t ws_size,
                              hipStream_t stream){
  const float* x     = (const float*)d_in[0];
  const float* w_qkv = (const float*)d_in[1];
  const float* b_qkv = (const float*)d_in[2];
  const float* w_out = (const float*)d_in[3];
  const float* b_out = (const float*)d_in[4];
  const float* cosb  = (const float*)d_in[5];
  const float* sinb  = (const float*)d_in[6];
  // d_in[7] = mask: causal, implemented analytically.
  float* out = (float*)d_out;
  char* ws = (char*)d_ws;
  u16* qkv  = (u16*)(ws);               // bf16 [4096][3072]   25.2 MB
  u16* attn = (u16*)(ws + 25165824);    // bf16 [4096][1024]    8.4 MB
  u16* xbf  = attn;                     // x bf16 — dead before flash writes attn
  u16* wT2  = (u16*)(ws + 33554432);    // w_out^T bf16 [1024][1024]  2.1 MB
  u16* wT1  = (u16*)(ws + 35651584);    // w_qkv^T bf16 [3072][1024]  6.3 MB
  u16* vT   = (u16*)(ws + 35651584);    // vT — overlaps wT1 (dead after GEMM1)

  transpose64<<<dim3(48, 16), 256, 0, stream>>>(w_qkv, wT1, 1024, 3072);
  transpose64<<<dim3(16, 16), 256, 0, stream>>>(w_out, wT2, 1024, 1024);
  convert_bf16<<<2048, 256, 0, stream>>>(x, xbf);
  gemm_bt<false, true ><<<dim3(24, 32), 256, 0, stream>>>(xbf, wT1, b_qkv, qkv,
                                                          4096, 3072, 1024, cosb, sinb);
  v_transpose<<<dim3(32, 32), 256, 0, stream>>>(qkv, vT);
  flash_attn<<<2048, 64, 0, stream>>>(qkv, vT, attn);
  gemm_bt<true , false><<<dim3(8, 32), 256, 0, stream>>>(attn, wT2, b_out, out,
                                                         4096, 1024, 1024, cosb, sinb);
}

// Round 18
// 134.381 us; speedup vs baseline: 1.2057x; 1.1685x over previous
//
#include <hip/hip_runtime.h>
#include <stdint.h>

typedef unsigned short u16;
typedef __attribute__((ext_vector_type(8))) __bf16 bf16x8;
typedef __attribute__((ext_vector_type(4))) float f32x4;
typedef __attribute__((ext_vector_type(4))) unsigned short u16x4;

__device__ __forceinline__ float bf2f(u16 u){
  unsigned int x = ((unsigned int)u) << 16;
  return __builtin_bit_cast(float, x);
}
// native f32->bf16 (RNE): compiler emits v_cvt_pk_bf16_f32 for pairs
__device__ __forceinline__ u16 f2bf(float f){
  return __builtin_bit_cast(u16, (__bf16)f);
}
__device__ __forceinline__ float fexp2(float x){ return __builtin_exp2f(x); }
// global -> LDS direct DMA, 16B/lane. LDS dest = wave-uniform base (+lane*16).
__device__ __forceinline__ void lds_load16(const void* g, void* l){
  __builtin_amdgcn_global_load_lds(
      (const __attribute__((address_space(1))) unsigned int*)g,
      (__attribute__((address_space(3))) unsigned int*)l, 16, 0, 0);
}

// ------- transpose+convert: out_bf16[C][R] = in_f32[R][C], 64x64 tiles -------
__global__ __launch_bounds__(256) void transpose64(const float* __restrict__ in,
                                                   u16* __restrict__ out,
                                                   int R, int C){
  __shared__ u16 t[64][65];
  const int c0 = blockIdx.x * 64, r0 = blockIdx.y * 64;
  const int tid = threadIdx.x;
  const int rr = tid >> 3;          // 0..31
  const int cc = (tid & 7) * 8;     // 0..56
#pragma unroll
  for (int i = 0; i < 2; i++){
    int r = i * 32 + rr;
    const float* p = in + (size_t)(r0 + r) * C + c0 + cc;
    f32x4 v0 = *(const f32x4*)p;
    f32x4 v1 = *(const f32x4*)(p + 4);
#pragma unroll
    for (int j = 0; j < 4; j++){ t[r][cc + j] = f2bf(v0[j]); t[r][cc + 4 + j] = f2bf(v1[j]); }
  }
  __syncthreads();
#pragma unroll
  for (int i = 0; i < 2; i++){
    int c = i * 32 + rr;
    u16 tmp[8];
#pragma unroll
    for (int j = 0; j < 8; j++) tmp[j] = t[cc + j][c];
    *(bf16x8*)(out + (size_t)(c0 + c) * R + r0 + cc) = *(const bf16x8*)tmp;
  }
}

// ------- x (f32) -> bf16 flat convert ----------------------------------------
__global__ __launch_bounds__(256) void convert_bf16(const float* __restrict__ in,
                                                    u16* __restrict__ out){
  int t = blockIdx.x * 256 + threadIdx.x;
  const float* p = in + (size_t)t * 8;
  f32x4 v0 = *(const f32x4*)p;
  f32x4 v1 = *(const f32x4*)(p + 4);
  u16 tmp[8];
#pragma unroll
  for (int j = 0; j < 4; j++){ tmp[j] = f2bf(v0[j]); tmp[4 + j] = f2bf(v1[j]); }
  *(bf16x8*)(out + (size_t)t * 8) = *(const bf16x8*)tmp;
}

// ------- vT[bh][d=64][s=2048] = V third of qkv, per-head transposed ----------
__global__ __launch_bounds__(256) void v_transpose(const u16* __restrict__ qkv,
                                                   u16* __restrict__ vT){
  const int S = 2048, LD = 3072;
  __shared__ u16 t[64][65];
  const int bh = blockIdx.y;
  const int b = bh >> 4, h = bh & 15;
  const int s0 = blockIdx.x * 64;
  const u16* src = qkv + (size_t)b * S * LD + 2048 + h * 64;
  const int tid = threadIdx.x;
  const int rr = tid >> 3;
  const int cc = (tid & 7) * 8;
#pragma unroll
  for (int i = 0; i < 2; i++){
    int s = i * 32 + rr;
    bf16x8 v = *(const bf16x8*)(src + (size_t)(s0 + s) * LD + cc);
#pragma unroll
    for (int j = 0; j < 8; j++) t[s][cc + j] = __builtin_bit_cast(u16, (__bf16)v[j]);
  }
  __syncthreads();
  u16* dst = vT + (size_t)bh * 64 * S;
#pragma unroll
  for (int i = 0; i < 2; i++){
    int d = i * 32 + rr;
    u16 tmp[8];
#pragma unroll
    for (int j = 0; j < 8; j++) tmp[j] = t[cc + j][d];
    *(bf16x8*)(dst + (size_t)d * S + s0 + cc) = *(const bf16x8*)tmp;
  }
}

// -------- GEMM (all-bf16, m97 DMA staging + XCD swizzle) ---------------------
// ROPE: fuse RoPE into epilogue for q/k columns (bn<16, wave-uniform).
template<bool OUTF32, bool ROPE>
__global__ __launch_bounds__(256, 2) void gemm_bt(const u16* __restrict__ A,
                                                  const u16* __restrict__ Bt,
                                                  const float* __restrict__ bias,
                                                  void* __restrict__ Cv,
                                                  int M, int N, int K,
                                                  const float* __restrict__ cosb,
                                                  const float* __restrict__ sinb){
  __shared__ u16 As[128 * 32];
  __shared__ u16 Bs[128 * 32];
  // bijective XCD chunking (nwg % 8 == 0 for both call sites)
  const int nx = gridDim.x;
  const int L = blockIdx.x + nx * blockIdx.y;
  const int per = (nx * gridDim.y) >> 3;
  const int wg = (L & 7) * per + (L >> 3);
  const int bn = wg % nx, bm = wg / nx;
  const int tid = threadIdx.x, w = tid >> 6, l = tid & 63;
  const int lo = l & 15, hi = l >> 4;
  const int wr = (w >> 1) * 64, wc = (w & 1) * 64;
  f32x4 acc[4][4] = {};
  const int lrow = l >> 2, lcd = l & 3;   // lane -> row-in-16, chunk

  for (int k0 = 0; k0 < K; k0 += 32){
#pragma unroll
    for (int i = 0; i < 2; i++){
      int row0 = i * 64 + w * 16;
      int row = row0 + lrow;
      int cs = lcd ^ ((row >> 1) & 3);    // pre-swizzled source chunk
      lds_load16(A  + (size_t)(bm * 128 + row) * K + k0 + cs * 8,
                 (char*)As + row0 * 64);
      lds_load16(Bt + (size_t)(bn * 128 + row) * K + k0 + cs * 8,
                 (char*)Bs + row0 * 64);
    }
    __syncthreads();
    bf16x8 a[4], b[4];
#pragma unroll
    for (int mi = 0; mi < 4; mi++){
      int row = wr + mi * 16 + lo;
      unsigned byte = (unsigned)(row * 64 + hi * 16) ^ (((row >> 1) & 3) << 4);
      a[mi] = *(const bf16x8*)((const char*)As + byte);
    }
#pragma unroll
    for (int ni = 0; ni < 4; ni++){
      int row = wc + ni * 16 + lo;
      unsigned byte = (unsigned)(row * 64 + hi * 16) ^ (((row >> 1) & 3) << 4);
      b[ni] = *(const bf16x8*)((const char*)Bs + byte);
    }
    __builtin_amdgcn_s_setprio(1);
#pragma unroll
    for (int mi = 0; mi < 4; mi++)
#pragma unroll
      for (int ni = 0; ni < 4; ni++)
        acc[mi][ni] = __builtin_amdgcn_mfma_f32_16x16x32_bf16(a[mi], b[ni], acc[mi][ni], 0, 0, 0);
    __builtin_amdgcn_s_setprio(0);
    __syncthreads();
  }
  if (ROPE && bn < 16){
    // q/k epilogue: val = acc + bias, then rope pair (even,odd col) via shfl
#pragma unroll
    for (int mi = 0; mi < 4; mi++){
#pragma unroll
      for (int r = 0; r < 4; r++){
        int grow = bm * 128 + wr + mi * 16 + hi * 4 + r;
        int stok = grow & 2047;
#pragma unroll
        for (int ni = 0; ni < 4; ni++){
          int col = bn * 128 + wc + ni * 16 + lo;
          float v = acc[mi][ni][r] + bias[col];
          float partner = __shfl_xor(v, 1, 64);
          int ip = (col & 63) >> 1;
          float c = cosb[stok * 32 + ip], sn = sinb[stok * 32 + ip];
          float res = (lo & 1) ? (partner * sn + v * c) : (v * c - partner * sn);
          ((u16*)Cv)[(size_t)grow * N + col] = f2bf(res);
        }
      }
    }
  } else {
#pragma unroll
    for (int mi = 0; mi < 4; mi++){
#pragma unroll
      for (int r = 0; r < 4; r++){
        int grow = bm * 128 + wr + mi * 16 + hi * 4 + r;
#pragma unroll
        for (int ni = 0; ni < 4; ni++){
          int col = bn * 128 + wc + ni * 16 + lo;
          float v = acc[mi][ni][r] + bias[col];
          if (OUTF32)
            ((float*)Cv)[(size_t)grow * N + col] = v;
          else
            ((u16*)Cv)[(size_t)grow * N + col] = f2bf(v);
        }
      }
    }
  }
}

// ---- flash attention: 1-wave blocks, 32 q-rows/wave, shared K/V per tile ----
// Grid 2048 = 32 bh x 64 pairs. bh = L & 31 (head pinned to one XCD);
// p = 63 - (L>>5) heavy-first; wave owns q-tiles {2p, 2p+1} (rows q0..q0+31).
// Per 32-key iteration: ONE K stage + ONE V load feed TWO QK/softmax/PV
// pipelines (A: rows q0+lo, B: rows q0+16+lo) -> halves K/V traffic and
// iteration count vs 16-row waves; amortizes chain latency over 2x work.
// nkt = p+1 exactly; only last tile masks. No __syncthreads anywhere.
__global__ __launch_bounds__(64, 4) void flash_attn(const u16* __restrict__ qkv,
                                                    const u16* __restrict__ vT,
                                                    u16* __restrict__ Oout){
  const int S = 2048, LD = 3072;
  const int L = blockIdx.x;
  const int bh = L & 31;
  const int p = 63 - (L >> 5);
  const int b = bh >> 4, h = bh & 15;
  const u16* base = qkv + (size_t)b * S * LD;
  const u16* Qp = base + h * 64;
  const u16* Kp = base + 1024 + h * 64;
  const u16* Vb = vT + (size_t)bh * 64 * S;
  const int l = threadIdx.x & 63;
  const int lo = l & 15, hi = l >> 4;
  __shared__ u16 Ks[2][32 * 64];            // 32 keys x 64 d, double-buffered
  __shared__ u16 PsA[16 * 36];              // P roundtrips, 72B row stride
  __shared__ u16 PsB[16 * 36];

  const float QSC = 0.125f * 1.44269504089f;  // -> log2 domain
  const int srow8 = l >> 3;
  const int scs = (l & 7) ^ srow8;          // DMA source chunk (row&7==l>>3)

  const int q0 = p * 32;
  const int qrowA = q0 + lo;
  const int qrowB = q0 + 16 + lo;
  const int nkt = p + 1;                    // 32-key tiles

  bf16x8 qfA0, qfA1, qfB0, qfB1;
  {
    bf16x8 va0 = *(const bf16x8*)(Qp + (size_t)qrowA * LD + hi * 8);
    bf16x8 va1 = *(const bf16x8*)(Qp + (size_t)qrowA * LD + 32 + hi * 8);
    bf16x8 vb0 = *(const bf16x8*)(Qp + (size_t)qrowB * LD + hi * 8);
    bf16x8 vb1 = *(const bf16x8*)(Qp + (size_t)qrowB * LD + 32 + hi * 8);
#pragma unroll
    for (int j = 0; j < 8; j++){
      qfA0[j] = (__bf16)((float)va0[j] * QSC);
      qfA1[j] = (__bf16)((float)va1[j] * QSC);
      qfB0[j] = (__bf16)((float)vb0[j] * QSC);
      qfB1[j] = (__bf16)((float)vb1[j] * QSC);
    }
  }

  f32x4 oA[4] = {}, oB[4] = {};
  float m_rA = -1e30f, l_parA = 0.f;
  float m_rB = -1e30f, l_parB = 0.f;

  // prologue: stage K tile 0 into buf 0 (4 x 1KB issues)
#pragma unroll
  for (int i = 0; i < 4; i++)
    lds_load16(Kp + (size_t)(i * 8 + srow8) * LD + scs * 8,
               (char*)&Ks[0][0] + i * 1024);

  int cur = 0;
  for (int kt = 0; kt < nkt; kt++){
    // ---- shared V^T B-frags (L2-resident; consumed at PV) ----
    bf16x8 vb[4];
#pragma unroll
    for (int fd = 0; fd < 4; fd++)
      vb[fd] = *(const bf16x8*)(Vb + (size_t)(fd * 16 + lo) * S + kt * 32 + hi * 8);
    // ---- shared K frags from Ks[cur] ----
    bf16x8 kb[2][2];
#pragma unroll
    for (int c = 0; c < 2; c++)
#pragma unroll
      for (int f = 0; f < 2; f++){
        int srow = f * 16 + lo;
        unsigned byte = ((unsigned)(srow * 128 + c * 64 + hi * 16)) ^ ((lo & 7) << 4);
        kb[c][f] = *(const bf16x8*)((const char*)&Ks[cur][0] + byte);
      }
    // ---- issue next K stage (prefetch, drains next iteration) ----
    if (kt + 1 < nkt){
#pragma unroll
      for (int i = 0; i < 4; i++)
        lds_load16(Kp + (size_t)((kt + 1) * 32 + i * 8 + srow8) * LD + scs * 8,
                   (char*)&Ks[cur ^ 1][0] + i * 1024);
    }
    // ---- S^T = K * Q^T for both q-tiles (log2 domain) ----
    f32x4 saA[2] = {}, saB[2] = {};
    __builtin_amdgcn_s_setprio(1);
#pragma unroll
    for (int f = 0; f < 2; f++){
      saA[f] = __builtin_amdgcn_mfma_f32_16x16x32_bf16(kb[0][f], qfA0, saA[f], 0, 0, 0);
      saB[f] = __builtin_amdgcn_mfma_f32_16x16x32_bf16(kb[0][f], qfB0, saB[f], 0, 0, 0);
      saA[f] = __builtin_amdgcn_mfma_f32_16x16x32_bf16(kb[1][f], qfA1, saA[f], 0, 0, 0);
      saB[f] = __builtin_amdgcn_mfma_f32_16x16x32_bf16(kb[1][f], qfB1, saB[f], 0, 0, 0);
    }
    __builtin_amdgcn_s_setprio(0);
    // ---- causal mask: only the last K-tile can cross either diagonal ----
    if (kt == nkt - 1){
#pragma unroll
      for (int f = 0; f < 2; f++){
        int key0 = kt * 32 + f * 16 + hi * 4;
#pragma unroll
        for (int r = 0; r < 4; r++){
          if (key0 + r > qrowA) saA[f][r] = -1e30f;
          if (key0 + r > qrowB) saB[f][r] = -1e30f;
        }
      }
    }
    // ---- defer-max online softmax x2 (independent chains -> ILP) ----
    float pmaxA = fmaxf(
        fmaxf(fmaxf(saA[0][0], saA[0][1]), fmaxf(saA[0][2], saA[0][3])),
        fmaxf(fmaxf(saA[1][0], saA[1][1]), fmaxf(saA[1][2], saA[1][3])));
    float pmaxB = fmaxf(
        fmaxf(fmaxf(saB[0][0], saB[0][1]), fmaxf(saB[0][2], saB[0][3])),
        fmaxf(fmaxf(saB[1][0], saB[1][1]), fmaxf(saB[1][2], saB[1][3])));
    if (!__all(fmaxf(pmaxA - m_rA, pmaxB - m_rB) <= 11.5f)){
      float rmA = fmaxf(pmaxA, __shfl_xor(pmaxA, 16, 64));
      rmA = fmaxf(rmA, __shfl_xor(rmA, 32, 64));
      float rmB = fmaxf(pmaxB, __shfl_xor(pmaxB, 16, 64));
      rmB = fmaxf(rmB, __shfl_xor(rmB, 32, 64));
      float mnA = fmaxf(m_rA, rmA), mnB = fmaxf(m_rB, rmB);
      float corrA = fexp2(m_rA - mnA), corrB = fexp2(m_rB - mnB);
      m_rA = mnA; m_rB = mnB;
      l_parA *= corrA; l_parB *= corrB;
      float cqA[4], cqB[4];
#pragma unroll
      for (int r = 0; r < 4; r++){
        cqA[r] = __shfl(corrA, hi * 4 + r, 64);
        cqB[r] = __shfl(corrB, hi * 4 + r, 64);
      }
#pragma unroll
      for (int fd = 0; fd < 4; fd++)
#pragma unroll
        for (int r = 0; r < 4; r++){ oA[fd][r] *= cqA[r]; oB[fd][r] *= cqB[r]; }
    }
    // exp2 -> pack+write P (LDS latency overlaps sums), then sums
    float pvA[2][4], pvB[2][4];
#pragma unroll
    for (int f = 0; f < 2; f++)
#pragma unroll
      for (int r = 0; r < 4; r++){
        pvA[f][r] = fexp2(saA[f][r] - m_rA);
        pvB[f][r] = fexp2(saB[f][r] - m_rB);
      }
#pragma unroll
    for (int f = 0; f < 2; f++){
      u16x4 pkA, pkB;
#pragma unroll
      for (int r = 0; r < 4; r++){ pkA[r] = f2bf(pvA[f][r]); pkB[r] = f2bf(pvB[f][r]); }
      *(u16x4*)((char*)PsA + lo * 72 + f * 32 + hi * 8) = pkA;
      *(u16x4*)((char*)PsB + lo * 72 + f * 32 + hi * 8) = pkB;
    }
    l_parA += ((pvA[0][0] + pvA[0][1]) + (pvA[0][2] + pvA[0][3]))
            + ((pvA[1][0] + pvA[1][1]) + (pvA[1][2] + pvA[1][3]));
    l_parB += ((pvB[0][0] + pvB[0][1]) + (pvB[0][2] + pvB[0][3]))
            + ((pvB[1][0] + pvB[1][1]) + (pvB[1][2] + pvB[1][3]));
    // ---- P read back as A-frags ----
    bf16x8 paA = *(const bf16x8*)((const char*)PsA + lo * 72 + hi * 16);
    bf16x8 paB = *(const bf16x8*)((const char*)PsB + lo * 72 + hi * 16);
    // ---- O += P V (shared vb) ----
    __builtin_amdgcn_s_setprio(1);
#pragma unroll
    for (int fd = 0; fd < 4; fd++){
      oA[fd] = __builtin_amdgcn_mfma_f32_16x16x32_bf16(paA, vb[fd], oA[fd], 0, 0, 0);
      oB[fd] = __builtin_amdgcn_mfma_f32_16x16x32_bf16(paB, vb[fd], oB[fd], 0, 0, 0);
    }
    __builtin_amdgcn_s_setprio(0);
    cur ^= 1;
  }
  // ---- final l reduce + normalize + store (both tiles) ----
  float lsA = l_parA, lsB = l_parB;
  lsA += __shfl_xor(lsA, 16, 64); lsA += __shfl_xor(lsA, 32, 64);
  lsB += __shfl_xor(lsB, 16, 64); lsB += __shfl_xor(lsB, 32, 64);
  float liA = 1.0f / lsA, liB = 1.0f / lsB;
  float iqA[4], iqB[4];
#pragma unroll
  for (int r = 0; r < 4; r++){
    iqA[r] = __shfl(liA, hi * 4 + r, 64);
    iqB[r] = __shfl(liB, hi * 4 + r, 64);
  }
#pragma unroll
  for (int r = 0; r < 4; r++){
    int srA = q0 + hi * 4 + r;
    int srB = q0 + 16 + hi * 4 + r;
    u16* orA = Oout + (size_t)(b * S + srA) * 1024 + h * 64;
    u16* orB = Oout + (size_t)(b * S + srB) * 1024 + h * 64;
#pragma unroll
    for (int fd = 0; fd < 4; fd++){
      orA[fd * 16 + lo] = f2bf(oA[fd][r] * iqA[r]);
      orB[fd * 16 + lo] = f2bf(oB[fd][r] * iqB[r]);
    }
  }
}

extern "C" void kernel_launch(void* const* d_in, const int* in_sizes, int n_in,
                              void* d_out, int out_size, void* d_ws, size_t ws_size,
                              hipStream_t stream){
  const float* x     = (const float*)d_in[0];
  const float* w_qkv = (const float*)d_in[1];
  const float* b_qkv = (const float*)d_in[2];
  const float* w_out = (const float*)d_in[3];
  const float* b_out = (const float*)d_in[4];
  const float* cosb  = (const float*)d_in[5];
  const float* sinb  = (const float*)d_in[6];
  // d_in[7] = mask: causal, implemented analytically.
  float* out = (float*)d_out;
  char* ws = (char*)d_ws;
  u16* qkv  = (u16*)(ws);               // bf16 [4096][3072]   25.2 MB
  u16* attn = (u16*)(ws + 25165824);    // bf16 [4096][1024]    8.4 MB
  u16* xbf  = attn;                     // x bf16 — dead before flash writes attn
  u16* wT2  = (u16*)(ws + 33554432);    // w_out^T bf16 [1024][1024]  2.1 MB
  u16* wT1  = (u16*)(ws + 35651584);    // w_qkv^T bf16 [3072][1024]  6.3 MB
  u16* vT   = (u16*)(ws + 35651584);    // vT — overlaps wT1 (dead after GEMM1)

  transpose64<<<dim3(48, 16), 256, 0, stream>>>(w_qkv, wT1, 1024, 3072);
  transpose64<<<dim3(16, 16), 256, 0, stream>>>(w_out, wT2, 1024, 1024);
  convert_bf16<<<2048, 256, 0, stream>>>(x, xbf);
  gemm_bt<false, true ><<<dim3(24, 32), 256, 0, stream>>>(xbf, wT1, b_qkv, qkv,
                                                          4096, 3072, 1024, cosb, sinb);
  v_transpose<<<dim3(32, 32), 256, 0, stream>>>(qkv, vT);
  flash_attn<<<2048, 64, 0, stream>>>(qkv, vT, attn);
  gemm_bt<true , false><<<dim3(8, 32), 256, 0, stream>>>(attn, wT2, b_out, out,
                                                         4096, 1024, 1024, cosb, sinb);
}

// Round 19
// 129.567 us; speedup vs baseline: 1.2505x; 1.0372x over previous
//
#include <hip/hip_runtime.h>
#include <stdint.h>

typedef unsigned short u16;
typedef __attribute__((ext_vector_type(8))) __bf16 bf16x8;
typedef __attribute__((ext_vector_type(4))) float f32x4;
typedef __attribute__((ext_vector_type(4))) unsigned short u16x4;

__device__ __forceinline__ float bf2f(u16 u){
  unsigned int x = ((unsigned int)u) << 16;
  return __builtin_bit_cast(float, x);
}
__device__ __forceinline__ u16 f2bf(float f){
  return __builtin_bit_cast(u16, (__bf16)f);
}
__device__ __forceinline__ float fexp2(float x){ return __builtin_exp2f(x); }
__device__ __forceinline__ void lds_load16(const void* g, void* l){
  __builtin_amdgcn_global_load_lds(
      (const __attribute__((address_space(1))) unsigned int*)g,
      (__attribute__((address_space(3))) unsigned int*)l, 16, 0, 0);
}

// ------- transpose+convert: out_bf16[C][R] = in_f32[R][C], 64x64 tiles -------
__global__ __launch_bounds__(256) void transpose64(const float* __restrict__ in,
                                                   u16* __restrict__ out,
                                                   int R, int C){
  __shared__ u16 t[64][65];
  const int c0 = blockIdx.x * 64, r0 = blockIdx.y * 64;
  const int tid = threadIdx.x;
  const int rr = tid >> 3;
  const int cc = (tid & 7) * 8;
#pragma unroll
  for (int i = 0; i < 2; i++){
    int r = i * 32 + rr;
    const float* p = in + (size_t)(r0 + r) * C + c0 + cc;
    f32x4 v0 = *(const f32x4*)p;
    f32x4 v1 = *(const f32x4*)(p + 4);
#pragma unroll
    for (int j = 0; j < 4; j++){ t[r][cc + j] = f2bf(v0[j]); t[r][cc + 4 + j] = f2bf(v1[j]); }
  }
  __syncthreads();
#pragma unroll
  for (int i = 0; i < 2; i++){
    int c = i * 32 + rr;
    u16 tmp[8];
#pragma unroll
    for (int j = 0; j < 8; j++) tmp[j] = t[cc + j][c];
    *(bf16x8*)(out + (size_t)(c0 + c) * R + r0 + cc) = *(const bf16x8*)tmp;
  }
}

// ------- x (f32) -> bf16 flat convert ----------------------------------------
__global__ __launch_bounds__(256) void convert_bf16(const float* __restrict__ in,
                                                    u16* __restrict__ out){
  int t = blockIdx.x * 256 + threadIdx.x;
  const float* p = in + (size_t)t * 8;
  f32x4 v0 = *(const f32x4*)p;
  f32x4 v1 = *(const f32x4*)(p + 4);
  u16 tmp[8];
#pragma unroll
  for (int j = 0; j < 4; j++){ tmp[j] = f2bf(v0[j]); tmp[4 + j] = f2bf(v1[j]); }
  *(bf16x8*)(out + (size_t)t * 8) = *(const bf16x8*)tmp;
}

// ------- vT[bh][d=64][s=2048] = V third of qkv, per-head transposed ----------
__global__ __launch_bounds__(256) void v_transpose(const u16* __restrict__ qkv,
                                                   u16* __restrict__ vT){
  const int S = 2048, LD = 3072;
  __shared__ u16 t[64][65];
  const int bh = blockIdx.y;
  const int b = bh >> 4, h = bh & 15;
  const int s0 = blockIdx.x * 64;
  const u16* src = qkv + (size_t)b * S * LD + 2048 + h * 64;
  const int tid = threadIdx.x;
  const int rr = tid >> 3;
  const int cc = (tid & 7) * 8;
#pragma unroll
  for (int i = 0; i < 2; i++){
    int s = i * 32 + rr;
    bf16x8 v = *(const bf16x8*)(src + (size_t)(s0 + s) * LD + cc);
#pragma unroll
    for (int j = 0; j < 8; j++) t[s][cc + j] = __builtin_bit_cast(u16, (__bf16)v[j]);
  }
  __syncthreads();
  u16* dst = vT + (size_t)bh * 64 * S;
#pragma unroll
  for (int i = 0; i < 2; i++){
    int d = i * 32 + rr;
    u16 tmp[8];
#pragma unroll
    for (int j = 0; j < 8; j++) tmp[j] = t[cc + j][d];
    *(bf16x8*)(dst + (size_t)d * S + s0 + cc) = *(const bf16x8*)tmp;
  }
}

// -------- GEMM (all-bf16, m97 DMA staging + XCD swizzle) ---------------------
template<bool OUTF32, bool ROPE>
__global__ __launch_bounds__(256, 2) void gemm_bt(const u16* __restrict__ A,
                                                  const u16* __restrict__ Bt,
                                                  const float* __restrict__ bias,
                                                  void* __restrict__ Cv,
                                                  int M, int N, int K,
                                                  const float* __restrict__ cosb,
                                                  const float* __restrict__ sinb){
  __shared__ u16 As[128 * 32];
  __shared__ u16 Bs[128 * 32];
  const int nx = gridDim.x;
  const int L = blockIdx.x + nx * blockIdx.y;
  const int per = (nx * gridDim.y) >> 3;
  const int wg = (L & 7) * per + (L >> 3);
  const int bn = wg % nx, bm = wg / nx;
  const int tid = threadIdx.x, w = tid >> 6, l = tid & 63;
  const int lo = l & 15, hi = l >> 4;
  const int wr = (w >> 1) * 64, wc = (w & 1) * 64;
  f32x4 acc[4][4] = {};
  const int lrow = l >> 2, lcd = l & 3;

  for (int k0 = 0; k0 < K; k0 += 32){
#pragma unroll
    for (int i = 0; i < 2; i++){
      int row0 = i * 64 + w * 16;
      int row = row0 + lrow;
      int cs = lcd ^ ((row >> 1) & 3);
      lds_load16(A  + (size_t)(bm * 128 + row) * K + k0 + cs * 8,
                 (char*)As + row0 * 64);
      lds_load16(Bt + (size_t)(bn * 128 + row) * K + k0 + cs * 8,
                 (char*)Bs + row0 * 64);
    }
    __syncthreads();
    bf16x8 a[4], b[4];
#pragma unroll
    for (int mi = 0; mi < 4; mi++){
      int row = wr + mi * 16 + lo;
      unsigned byte = (unsigned)(row * 64 + hi * 16) ^ (((row >> 1) & 3) << 4);
      a[mi] = *(const bf16x8*)((const char*)As + byte);
    }
#pragma unroll
    for (int ni = 0; ni < 4; ni++){
      int row = wc + ni * 16 + lo;
      unsigned byte = (unsigned)(row * 64 + hi * 16) ^ (((row >> 1) & 3) << 4);
      b[ni] = *(const bf16x8*)((const char*)Bs + byte);
    }
    __builtin_amdgcn_s_setprio(1);
#pragma unroll
    for (int mi = 0; mi < 4; mi++)
#pragma unroll
      for (int ni = 0; ni < 4; ni++)
        acc[mi][ni] = __builtin_amdgcn_mfma_f32_16x16x32_bf16(a[mi], b[ni], acc[mi][ni], 0, 0, 0);
    __builtin_amdgcn_s_setprio(0);
    __syncthreads();
  }
  if (ROPE && bn < 16){
#pragma unroll
    for (int mi = 0; mi < 4; mi++){
#pragma unroll
      for (int r = 0; r < 4; r++){
        int grow = bm * 128 + wr + mi * 16 + hi * 4 + r;
        int stok = grow & 2047;
#pragma unroll
        for (int ni = 0; ni < 4; ni++){
          int col = bn * 128 + wc + ni * 16 + lo;
          float v = acc[mi][ni][r] + bias[col];
          float partner = __shfl_xor(v, 1, 64);
          int ip = (col & 63) >> 1;
          float c = cosb[stok * 32 + ip], sn = sinb[stok * 32 + ip];
          float res = (lo & 1) ? (partner * sn + v * c) : (v * c - partner * sn);
          ((u16*)Cv)[(size_t)grow * N + col] = f2bf(res);
        }
      }
    }
  } else {
#pragma unroll
    for (int mi = 0; mi < 4; mi++){
#pragma unroll
      for (int r = 0; r < 4; r++){
        int grow = bm * 128 + wr + mi * 16 + hi * 4 + r;
#pragma unroll
        for (int ni = 0; ni < 4; ni++){
          int col = bn * 128 + wc + ni * 16 + lo;
          float v = acc[mi][ni][r] + bias[col];
          if (OUTF32)
            ((float*)Cv)[(size_t)grow * N + col] = v;
          else
            ((u16*)Cv)[(size_t)grow * N + col] = f2bf(v);
        }
      }
    }
  }
}

// ---- flash attention: 2-wave blocks, split-K halves + tile pairing ----------
// Block bx handles q-tiles T0=63-bx, T1=bx (32 rows each). Wave w processes
// HALF of each tile's K-range (w=0: [0,c), w=1: [c,nkt)) with the r18 inner
// loop (A/B 16-row sub-tiles, shared K stage + V loads, defer-max, log2).
// Per-wave iterations = ceil((64-bx)/2)+ceil((bx+1)/2) = 33/32 UNIFORM -> no
// tail; 1024 blocks = 4/CU all resident. Partials merge via LDS exchange:
// wave1 writes T0 partial (bf16 O col-major + m/l), wave0 writes T1 partial;
// one barrier; symmetric read-back and flash-merge in registers.
#define FA_PHASE(T_, OA_, OB_, MA_, MB_, LA_, LB_)                             \
  {                                                                            \
    const int q0p = (T_) * 32;                                                 \
    const int qrA = q0p + lo, qrB = q0p + 16 + lo;                             \
    const int nkt = (T_) + 1;                                                  \
    const int ch = (nkt + 1) >> 1;                                             \
    const int k0 = w ? ch : 0;                                                 \
    const int k1 = w ? nkt : ch;                                               \
    bf16x8 qfA0, qfA1, qfB0, qfB1;                                             \
    {                                                                          \
      bf16x8 va0 = *(const bf16x8*)(Qp + (size_t)qrA * LD + hi * 8);           \
      bf16x8 va1 = *(const bf16x8*)(Qp + (size_t)qrA * LD + 32 + hi * 8);      \
      bf16x8 vb0 = *(const bf16x8*)(Qp + (size_t)qrB * LD + hi * 8);           \
      bf16x8 vb1 = *(const bf16x8*)(Qp + (size_t)qrB * LD + 32 + hi * 8);      \
      _Pragma("unroll")                                                        \
      for (int j = 0; j < 8; j++){                                             \
        qfA0[j] = (__bf16)((float)va0[j] * QSC);                               \
        qfA1[j] = (__bf16)((float)va1[j] * QSC);                               \
        qfB0[j] = (__bf16)((float)vb0[j] * QSC);                               \
        qfB1[j] = (__bf16)((float)vb1[j] * QSC);                               \
      }                                                                        \
    }                                                                          \
    float lparA = 0.f, lparB = 0.f;                                            \
    MA_ = -1e30f; MB_ = -1e30f;                                                \
    if (k0 < k1){                                                              \
      _Pragma("unroll")                                                        \
      for (int i = 0; i < 4; i++)                                              \
        lds_load16(Kp + (size_t)(k0 * 32 + i * 8 + srow8) * LD + scs * 8,      \
                   (char*)&Ks[w][0][0] + i * 1024);                            \
    }                                                                          \
    int cur = 0;                                                               \
    for (int kt = k0; kt < k1; kt++){                                          \
      bf16x8 vb[4];                                                            \
      _Pragma("unroll")                                                        \
      for (int fd = 0; fd < 4; fd++)                                           \
        vb[fd] = *(const bf16x8*)(Vb + (size_t)(fd * 16 + lo) * S +            \
                                  kt * 32 + hi * 8);                           \
      bf16x8 kb[2][2];                                                         \
      _Pragma("unroll")                                                        \
      for (int c = 0; c < 2; c++){                                             \
        _Pragma("unroll")                                                      \
        for (int f = 0; f < 2; f++){                                           \
          int srw = f * 16 + lo;                                               \
          unsigned byte = ((unsigned)(srw * 128 + c * 64 + hi * 16)) ^         \
                          ((lo & 7) << 4);                                     \
          kb[c][f] = *(const bf16x8*)((const char*)&Ks[w][cur][0] + byte);     \
        }                                                                      \
      }                                                                        \
      if (kt + 1 < k1){                                                        \
        _Pragma("unroll")                                                      \
        for (int i = 0; i < 4; i++)                                            \
          lds_load16(Kp + (size_t)((kt + 1) * 32 + i * 8 + srow8) * LD +       \
                         scs * 8,                                              \
                     (char*)&Ks[w][cur ^ 1][0] + i * 1024);                    \
      }                                                                        \
      f32x4 saA[2] = {}, saB[2] = {};                                          \
      __builtin_amdgcn_s_setprio(1);                                           \
      _Pragma("unroll")                                                        \
      for (int f = 0; f < 2; f++){                                             \
        saA[f] = __builtin_amdgcn_mfma_f32_16x16x32_bf16(kb[0][f], qfA0,       \
                                                         saA[f], 0, 0, 0);     \
        saB[f] = __builtin_amdgcn_mfma_f32_16x16x32_bf16(kb[0][f], qfB0,       \
                                                         saB[f], 0, 0, 0);     \
        saA[f] = __builtin_amdgcn_mfma_f32_16x16x32_bf16(kb[1][f], qfA1,       \
                                                         saA[f], 0, 0, 0);     \
        saB[f] = __builtin_amdgcn_mfma_f32_16x16x32_bf16(kb[1][f], qfB1,       \
                                                         saB[f], 0, 0, 0);     \
      }                                                                        \
      __builtin_amdgcn_s_setprio(0);                                           \
      if (kt == nkt - 1){                                                      \
        _Pragma("unroll")                                                      \
        for (int f = 0; f < 2; f++){                                           \
          int key0 = kt * 32 + f * 16 + hi * 4;                                \
          _Pragma("unroll")                                                    \
          for (int r = 0; r < 4; r++){                                         \
            if (key0 + r > qrA) saA[f][r] = -1e30f;                            \
            if (key0 + r > qrB) saB[f][r] = -1e30f;                            \
          }                                                                    \
        }                                                                      \
      }                                                                        \
      float pmA = fmaxf(                                                       \
          fmaxf(fmaxf(saA[0][0], saA[0][1]), fmaxf(saA[0][2], saA[0][3])),     \
          fmaxf(fmaxf(saA[1][0], saA[1][1]), fmaxf(saA[1][2], saA[1][3])));    \
      float pmB = fmaxf(                                                       \
          fmaxf(fmaxf(saB[0][0], saB[0][1]), fmaxf(saB[0][2], saB[0][3])),     \
          fmaxf(fmaxf(saB[1][0], saB[1][1]), fmaxf(saB[1][2], saB[1][3])));    \
      if (!__all(fmaxf(pmA - MA_, pmB - MB_) <= 11.5f)){                       \
        float rmA = fmaxf(pmA, __shfl_xor(pmA, 16, 64));                       \
        rmA = fmaxf(rmA, __shfl_xor(rmA, 32, 64));                             \
        float rmB = fmaxf(pmB, __shfl_xor(pmB, 16, 64));                       \
        rmB = fmaxf(rmB, __shfl_xor(rmB, 32, 64));                             \
        float mnA = fmaxf(MA_, rmA), mnB = fmaxf(MB_, rmB);                    \
        float cA = fexp2(MA_ - mnA), cB = fexp2(MB_ - mnB);                    \
        MA_ = mnA; MB_ = mnB;                                                  \
        lparA *= cA; lparB *= cB;                                              \
        float cqA[4], cqB[4];                                                  \
        _Pragma("unroll")                                                      \
        for (int r = 0; r < 4; r++){                                           \
          cqA[r] = __shfl(cA, hi * 4 + r, 64);                                 \
          cqB[r] = __shfl(cB, hi * 4 + r, 64);                                 \
        }                                                                      \
        _Pragma("unroll")                                                      \
        for (int fd = 0; fd < 4; fd++){                                        \
          _Pragma("unroll")                                                    \
          for (int r = 0; r < 4; r++){                                         \
            OA_[fd][r] *= cqA[r]; OB_[fd][r] *= cqB[r];                        \
          }                                                                    \
        }                                                                      \
      }                                                                        \
      float pvA[2][4], pvB[2][4];                                              \
      _Pragma("unroll")                                                        \
      for (int f = 0; f < 2; f++){                                             \
        _Pragma("unroll")                                                      \
        for (int r = 0; r < 4; r++){                                           \
          pvA[f][r] = fexp2(saA[f][r] - MA_);                                  \
          pvB[f][r] = fexp2(saB[f][r] - MB_);                                  \
        }                                                                      \
      }                                                                        \
      _Pragma("unroll")                                                        \
      for (int f = 0; f < 2; f++){                                             \
        u16x4 pkA, pkB;                                                        \
        _Pragma("unroll")                                                      \
        for (int r = 0; r < 4; r++){                                           \
          pkA[r] = f2bf(pvA[f][r]); pkB[r] = f2bf(pvB[f][r]);                  \
        }                                                                      \
        *(u16x4*)((char*)&Ps[w][0][0] + lo * 72 + f * 32 + hi * 8) = pkA;      \
        *(u16x4*)((char*)&Ps[w][1][0] + lo * 72 + f * 32 + hi * 8) = pkB;      \
      }                                                                        \
      lparA += ((pvA[0][0] + pvA[0][1]) + (pvA[0][2] + pvA[0][3]))             \
             + ((pvA[1][0] + pvA[1][1]) + (pvA[1][2] + pvA[1][3]));            \
      lparB += ((pvB[0][0] + pvB[0][1]) + (pvB[0][2] + pvB[0][3]))             \
             + ((pvB[1][0] + pvB[1][1]) + (pvB[1][2] + pvB[1][3]));            \
      bf16x8 paA = *(const bf16x8*)((const char*)&Ps[w][0][0] + lo * 72 +      \
                                    hi * 16);                                  \
      bf16x8 paB = *(const bf16x8*)((const char*)&Ps[w][1][0] + lo * 72 +      \
                                    hi * 16);                                  \
      __builtin_amdgcn_s_setprio(1);                                           \
      _Pragma("unroll")                                                        \
      for (int fd = 0; fd < 4; fd++){                                          \
        OA_[fd] = __builtin_amdgcn_mfma_f32_16x16x32_bf16(paA, vb[fd],         \
                                                          OA_[fd], 0, 0, 0);   \
        OB_[fd] = __builtin_amdgcn_mfma_f32_16x16x32_bf16(paB, vb[fd],         \
                                                          OB_[fd], 0, 0, 0);   \
      }                                                                        \
      __builtin_amdgcn_s_setprio(0);                                           \
      cur ^= 1;                                                                \
    }                                                                          \
    lparA += __shfl_xor(lparA, 16, 64); lparA += __shfl_xor(lparA, 32, 64);    \
    lparB += __shfl_xor(lparB, 16, 64); lparB += __shfl_xor(lparB, 32, 64);    \
    LA_ = lparA; LB_ = lparB;                                                  \
  }

#define FA_WRITEPART(slot_, OA_, OB_, MA_, MB_, LA_, LB_)                      \
  {                                                                            \
    _Pragma("unroll")                                                          \
    for (int fd = 0; fd < 4; fd++){                                            \
      u16x4 pkA, pkB;                                                          \
      _Pragma("unroll")                                                        \
      for (int r = 0; r < 4; r++){                                             \
        pkA[r] = f2bf(OA_[fd][r]); pkB[r] = f2bf(OB_[fd][r]);                  \
      }                                                                        \
      *(u16x4*)((char*)&Xo[slot_][0] + (fd * 16 + lo) * 64 + hi * 8) = pkA;    \
      *(u16x4*)((char*)&Xo[slot_][0] + (fd * 16 + lo) * 64 + 32 + hi * 8) = pkB;\
    }                                                                          \
    if (hi == 0){                                                              \
      Xm[slot_][lo] = MA_;      Xl[slot_][lo] = LA_;                           \
      Xm[slot_][16 + lo] = MB_; Xl[slot_][16 + lo] = LB_;                      \
    }                                                                          \
  }

#define FA_COMBINE(slot_, T_, OA_, OB_, MA_, MB_, LA_, LB_)                    \
  {                                                                            \
    const int q0p = (T_) * 32;                                                 \
    u16x4 pA[4], pB[4];                                                        \
    _Pragma("unroll")                                                          \
    for (int fd = 0; fd < 4; fd++){                                            \
      pA[fd] = *(const u16x4*)((const char*)&Xo[slot_][0] +                    \
                               (fd * 16 + lo) * 64 + hi * 8);                  \
      pB[fd] = *(const u16x4*)((const char*)&Xo[slot_][0] +                    \
                               (fd * 16 + lo) * 64 + 32 + hi * 8);             \
    }                                                                          \
    _Pragma("unroll")                                                          \
    for (int r = 0; r < 4; r++){                                               \
      float mOA = __shfl(MA_, hi * 4 + r, 64);                                 \
      float lOA = __shfl(LA_, hi * 4 + r, 64);                                 \
      float mOB = __shfl(MB_, hi * 4 + r, 64);                                 \
      float lOB = __shfl(LB_, hi * 4 + r, 64);                                 \
      float mPA = Xm[slot_][hi * 4 + r], lPA = Xl[slot_][hi * 4 + r];          \
      float mPB = Xm[slot_][16 + hi * 4 + r], lPB = Xl[slot_][16 + hi * 4 + r];\
      float MfA = fmaxf(mOA, mPA), MfB = fmaxf(mOB, mPB);                      \
      float c0A = fexp2(mOA - MfA), c1A = fexp2(mPA - MfA);                    \
      float c0B = fexp2(mOB - MfB), c1B = fexp2(mPB - MfB);                    \
      float invA = 1.0f / (lOA * c0A + lPA * c1A);                             \
      float invB = 1.0f / (lOB * c0B + lPB * c1B);                             \
      int srA = q0p + hi * 4 + r;                                              \
      int srB = q0p + 16 + hi * 4 + r;                                         \
      u16* orA = Oout + (size_t)(b * S + srA) * 1024 + h * 64;                 \
      u16* orB = Oout + (size_t)(b * S + srB) * 1024 + h * 64;                 \
      _Pragma("unroll")                                                        \
      for (int fd = 0; fd < 4; fd++){                                          \
        float vA = (OA_[fd][r] * c0A + bf2f(pA[fd][r]) * c1A) * invA;          \
        float vB = (OB_[fd][r] * c0B + bf2f(pB[fd][r]) * c1B) * invB;          \
        orA[fd * 16 + lo] = f2bf(vA);                                          \
        orB[fd * 16 + lo] = f2bf(vB);                                          \
      }                                                                        \
    }                                                                          \
  }

__global__ __launch_bounds__(128, 2) void flash_attn(const u16* __restrict__ qkv,
                                                     const u16* __restrict__ vT,
                                                     u16* __restrict__ Oout){
  const int S = 2048, LD = 3072;
  const int L = blockIdx.x;
  const int bh = L & 31;
  const int bx = L >> 5;                    // 0..31
  const int b = bh >> 4, h = bh & 15;
  const u16* base = qkv + (size_t)b * S * LD;
  const u16* Qp = base + h * 64;
  const u16* Kp = base + 1024 + h * 64;
  const u16* Vb = vT + (size_t)bh * 64 * S;
  const int tid = threadIdx.x, w = tid >> 6, l = tid & 63;
  const int lo = l & 15, hi = l >> 4;
  __shared__ u16 Ks[2][2][32 * 64];         // [wave][buf]
  __shared__ u16 Ps[2][2][16 * 36];         // [wave][subtile]
  __shared__ u16 Xo[2][32 * 64];            // [slot] partial O, col-major bf16
  __shared__ float Xm[2][32], Xl[2][32];

  const float QSC = 0.125f * 1.44269504089f;
  const int srow8 = l >> 3;
  const int scs = (l & 7) ^ srow8;

  f32x4 o1A[4] = {}, o1B[4] = {};           // phase1 (T0) partial
  f32x4 o2A[4] = {}, o2B[4] = {};           // phase2 (T1) partial
  float m1A, m1B, l1A, l1B, m2A, m2B, l2A, l2B;

  FA_PHASE(63 - bx, o1A, o1B, m1A, m1B, l1A, l1B);
  if (w == 1) FA_WRITEPART(0, o1A, o1B, m1A, m1B, l1A, l1B);
  FA_PHASE(bx,      o2A, o2B, m2A, m2B, l2A, l2B);
  if (w == 0) FA_WRITEPART(1, o2A, o2B, m2A, m2B, l2A, l2B);
  __syncthreads();
  if (w == 0){
    FA_COMBINE(0, 63 - bx, o1A, o1B, m1A, m1B, l1A, l1B);
  } else {
    FA_COMBINE(1, bx,      o2A, o2B, m2A, m2B, l2A, l2B);
  }
}

extern "C" void kernel_launch(void* const* d_in, const int* in_sizes, int n_in,
                              void* d_out, int out_size, void* d_ws, size_t ws_size,
                              hipStream_t stream){
  const float* x     = (const float*)d_in[0];
  const float* w_qkv = (const float*)d_in[1];
  const float* b_qkv = (const float*)d_in[2];
  const float* w_out = (const float*)d_in[3];
  const float* b_out = (const float*)d_in[4];
  const float* cosb  = (const float*)d_in[5];
  const float* sinb  = (const float*)d_in[6];
  // d_in[7] = mask: causal, implemented analytically.
  float* out = (float*)d_out;
  char* ws = (char*)d_ws;
  u16* qkv  = (u16*)(ws);               // bf16 [4096][3072]   25.2 MB
  u16* attn = (u16*)(ws + 25165824);    // bf16 [4096][1024]    8.4 MB
  u16* xbf  = attn;                     // x bf16 — dead before flash writes attn
  u16* wT2  = (u16*)(ws + 33554432);    // w_out^T bf16 [1024][1024]  2.1 MB
  u16* wT1  = (u16*)(ws + 35651584);    // w_qkv^T bf16 [3072][1024]  6.3 MB
  u16* vT   = (u16*)(ws + 35651584);    // vT — overlaps wT1 (dead after GEMM1)

  transpose64<<<dim3(48, 16), 256, 0, stream>>>(w_qkv, wT1, 1024, 3072);
  transpose64<<<dim3(16, 16), 256, 0, stream>>>(w_out, wT2, 1024, 1024);
  convert_bf16<<<2048, 256, 0, stream>>>(x, xbf);
  gemm_bt<false, true ><<<dim3(24, 32), 256, 0, stream>>>(xbf, wT1, b_qkv, qkv,
                                                          4096, 3072, 1024, cosb, sinb);
  v_transpose<<<dim3(32, 32), 256, 0, stream>>>(qkv, vT);
  flash_attn<<<1024, 128, 0, stream>>>(qkv, vT, attn);
  gemm_bt<true , false><<<dim3(8, 32), 256, 0, stream>>>(attn, wT2, b_out, out,
                                                         4096, 1024, 1024, cosb, sinb);
}